// Round 3
// baseline (277.035 us; speedup 1.0000x reference)
//
#include <hip/hip_runtime.h>
#include <hip/hip_bf16.h>
#include <math.h>

#define BB 4
#define CC 256
#define DKK 32
#define NN 4096
// 1/sqrt(32) * log2(e) — folded into q at QKV epilogue; attention uses exp2.
#define QSCALE 0.2550181864060454f

typedef __attribute__((ext_vector_type(8))) __bf16 bf16x8;
typedef __attribute__((ext_vector_type(4))) float f32x4;

// ---------------------------------------------------------------------------
// Kernel 0: convert W (Wq 32x256, Wk 32x256, Wv 256x256) fp32 -> bf16 Wb[320][256]
// ---------------------------------------------------------------------------
__global__ __launch_bounds__(256) void wconv_kernel(
    const float* __restrict__ Wq, const float* __restrict__ Wk,
    const float* __restrict__ Wv, __bf16* __restrict__ Wb)
{
    int i = (blockIdx.x * 256 + threadIdx.x) * 4;   // 80 blocks -> 81920 elems
    int row = i >> 8, col = i & 255;
    const float* src;
    if (row < 32)      src = &Wq[row * 256 + col];
    else if (row < 64) src = &Wk[(row - 32) * 256 + col];
    else               src = &Wv[(row - 64) * 256 + col];
    float4 v = *(const float4*)src;
    Wb[i]     = (__bf16)v.x;
    Wb[i + 1] = (__bf16)v.y;
    Wb[i + 2] = (__bf16)v.z;
    Wb[i + 3] = (__bf16)v.w;
}

// ---------------------------------------------------------------------------
// Kernel 1: QKV projection via bf16 MFMA.
// Per block: 32 n-columns x 320 output rows. 4 waves, wave w -> o 80w..80w+79.
// x staged transposed in LDS ([n][k], pad 72). W A-frags from global (L2-hot).
// Outputs: q,k (B,N,32) bf16 (q pre-scaled), v (B,C,N) bf16.
// q/k transposed to (n,d) through wave-0-private LDS scratch.
// ---------------------------------------------------------------------------
__global__ __launch_bounds__(256) void qkv_kernel(
    const float* __restrict__ x,
    const float* __restrict__ bq, const float* __restrict__ bk,
    const float* __restrict__ bv, const __bf16* __restrict__ Wb,
    __bf16* __restrict__ qws, __bf16* __restrict__ kws, __bf16* __restrict__ vws)
{
    __shared__ __align__(16) __bf16 xt[32 * 72];   // [n][k-chunk 64 + pad]
    __shared__ __align__(16) float qk_s[64 * 40];  // wave-0 q/k transpose scratch

    const int tid = threadIdx.x;
    const int w   = tid >> 6;
    const int l   = tid & 63;
    const int l15 = l & 15;
    const int lq  = l >> 4;
    const int n0  = blockIdx.x * 32;               // 128 n-tiles
    const int b   = blockIdx.y;

    const f32x4 zf = {0.f, 0.f, 0.f, 0.f};
    f32x4 acc[5][2];
#pragma unroll
    for (int i = 0; i < 5; i++)
#pragma unroll
        for (int j = 0; j < 2; j++) acc[i][j] = zf;

    for (int k0 = 0; k0 < CC; k0 += 64) {
        // stage x[k0..k0+63][n0..n0+31] transposed -> xt[n][k]
#pragma unroll
        for (int p2 = 0; p2 < 2; p2++) {
            int kk  = (tid >> 3) + p2 * 32;        // 0..63
            int nn4 = (tid & 7) * 4;
            float4 xv = *(const float4*)&x[((size_t)b * CC + k0 + kk) * NN + n0 + nn4];
            xt[(nn4 + 0) * 72 + kk] = (__bf16)xv.x;
            xt[(nn4 + 1) * 72 + kk] = (__bf16)xv.y;
            xt[(nn4 + 2) * 72 + kk] = (__bf16)xv.z;
            xt[(nn4 + 3) * 72 + kk] = (__bf16)xv.w;
        }
        __syncthreads();
#pragma unroll
        for (int ks = 0; ks < 2; ks++) {
            bf16x8 bfr[2];
#pragma unroll
            for (int nt = 0; nt < 2; nt++)
                bfr[nt] = *(const bf16x8*)&xt[(nt * 16 + l15) * 72 + ks * 32 + lq * 8];
#pragma unroll
            for (int ot = 0; ot < 5; ot++) {
                bf16x8 af = *(const bf16x8*)&Wb[(size_t)(80 * w + ot * 16 + l15) * CC
                                                + k0 + ks * 32 + lq * 8];
#pragma unroll
                for (int nt = 0; nt < 2; nt++)
                    acc[ot][nt] = __builtin_amdgcn_mfma_f32_16x16x32_bf16(af, bfr[nt], acc[ot][nt], 0, 0, 0);
            }
        }
        __syncthreads();
    }

    // epilogue: D row = 80w + ot*16 + lq*4 + r, col = n0 + nt*16 + l15
#pragma unroll
    for (int ot = 0; ot < 5; ot++) {
        int o_tile = 80 * w + ot * 16;             // tile never straddles 32/64
#pragma unroll
        for (int nt = 0; nt < 2; nt++) {
#pragma unroll
            for (int r = 0; r < 4; r++) {
                int o = o_tile + lq * 4 + r;
                float val = acc[ot][nt][r];
                if (o_tile >= 64) {
                    int c = o - 64;
                    vws[((size_t)b * CC + c) * NN + n0 + nt * 16 + l15] =
                        (__bf16)(val + bv[c]);
                } else if (o_tile < 32) {
                    qk_s[o * 40 + nt * 16 + l15] = (val + bq[o]) * QSCALE;
                } else {
                    qk_s[o * 40 + nt * 16 + l15] = val + bk[o - 32];
                }
            }
        }
    }

    if (w == 0) {
        __asm__ volatile("s_waitcnt lgkmcnt(0)" ::: "memory");
        int nn = l & 31, dh = l >> 5;
#pragma unroll
        for (int s = 0; s < 2; s++) {
            int d0 = dh * 16 + s * 8;
            bf16x8 qv, kv;
#pragma unroll
            for (int j = 0; j < 8; j++) {
                qv[j] = (__bf16)qk_s[(d0 + j) * 40 + nn];
                kv[j] = (__bf16)qk_s[(32 + d0 + j) * 40 + nn];
            }
            size_t base = ((size_t)b * NN + n0 + nn) * DKK + d0;
            *(bf16x8*)&qws[base] = qv;
            *(bf16x8*)&kws[base] = kv;
        }
    }
}

// ---------------------------------------------------------------------------
// Kernel 2: single-pass MFMA flash attention, m-tile = 32, grid 512 (2 blk/CU).
// Wave w: QK for m-half (w&1), n-cols 32*(w>>1)..+31; PV c-range 64w..64w+63.
// P: C-layout -> A-layout via double-buffered LDS, 1 barrier/chunk.
// ---------------------------------------------------------------------------
#define PST 88
#define PBUFSZ (32 * PST)

__global__ __launch_bounds__(256) void attn_kernel(
    const __bf16* __restrict__ qb, const __bf16* __restrict__ kb,
    const __bf16* __restrict__ vb, const float* __restrict__ x,
    float* __restrict__ out)
{
    __shared__ __align__(16) __bf16 Pbuf[2 * PBUFSZ];   // 11264 B
    __shared__ float Ls2[2][32];

    const int tid = threadIdx.x;
    const int w   = tid >> 6;
    const int l   = tid & 63;
    const int l15 = l & 15;
    const int lq  = l >> 4;
    const int h   = w & 1;          // m-half for QK
    const int p   = w >> 1;         // n-col pair for QK

    // XCD swizzle: batch b pinned to an XCD pair -> V L2-resident
    const int beta = blockIdx.x;
    const int b    = (beta >> 1) & 3;
    const int mt   = ((beta >> 3) << 1) | (beta & 1);   // 0..127
    const int m0   = mt * 32;

    const __bf16* qbb = qb + (size_t)b * NN * DKK;
    const __bf16* kbb = kb + (size_t)b * NN * DKK;
    const __bf16* vbb = vb + (size_t)b * CC * NN;

    bf16x8 qa = *(const bf16x8*)(qbb + (size_t)(m0 + h * 16 + l15) * DKK + lq * 8);

    const f32x4 zf = {0.f, 0.f, 0.f, 0.f};
    f32x4 acc[2][4];
#pragma unroll
    for (int i = 0; i < 2; i++)
#pragma unroll
        for (int j = 0; j < 4; j++) acc[i][j] = zf;
    float lacc[4] = {0.f, 0.f, 0.f, 0.f};

    for (int nc = 0; nc < NN; nc += 64) {
        __bf16* Pc = Pbuf + ((nc >> 6) & 1) * PBUFSZ;

        // ---- QK^T: this wave's 16m x 32n patch ----
        f32x4 e[2];
#pragma unroll
        for (int j = 0; j < 2; j++) {
            bf16x8 kf = *(const bf16x8*)(kbb + (size_t)(nc + (2 * p + j) * 16 + l15) * DKK + lq * 8);
            e[j] = __builtin_amdgcn_mfma_f32_16x16x32_bf16(qa, kf, zf, 0, 0, 0);
        }
#pragma unroll
        for (int j = 0; j < 2; j++) {
#pragma unroll
            for (int r = 0; r < 4; r++) {
                float ev = __builtin_exp2f(e[j][r]);
                lacc[r] += ev;
                Pc[(h * 16 + lq * 4 + r) * PST + (2 * p + j) * 16 + l15] = (__bf16)ev;
            }
        }
        __syncthreads();

        // ---- PV: O[m][c] += P[m][n] V[c][n], c-split across waves ----
#pragma unroll
        for (int ks = 0; ks < 2; ks++) {
            bf16x8 pf[2];
#pragma unroll
            for (int af = 0; af < 2; af++)
                pf[af] = *(const bf16x8*)&Pc[(af * 16 + l15) * PST + ks * 32 + lq * 8];
#pragma unroll
            for (int ct = 0; ct < 4; ct++) {
                bf16x8 vf = *(const bf16x8*)(vbb + (size_t)(w * 64 + ct * 16 + l15) * NN
                                             + nc + ks * 32 + lq * 8);
#pragma unroll
                for (int af = 0; af < 2; af++)
                    acc[af][ct] =
                        __builtin_amdgcn_mfma_f32_16x16x32_bf16(pf[af], vf, acc[af][ct], 0, 0, 0);
            }
        }
    }

    // ---- l: reduce across 16 n-lanes, publish per (p, m) ----
#pragma unroll
    for (int r = 0; r < 4; r++) {
#pragma unroll
        for (int msk = 1; msk <= 8; msk <<= 1)
            lacc[r] += __shfl_xor(lacc[r], msk, 16);
    }
    if (l15 == 0) {
#pragma unroll
        for (int r = 0; r < 4; r++) Ls2[p][h * 16 + lq * 4 + r] = lacc[r];
    }
    __syncthreads();

    // ---- epilogue: normalize, transpose (m,c)->(c,m) via wave-private LDS ----
    float* scr = (float*)Pbuf + w * (16 * 40);   // 2560 B/wave, overlays Pbuf
    f32x4 rcp[2];
#pragma unroll
    for (int af = 0; af < 2; af++) {
        f32x4 l0 = *(const f32x4*)&Ls2[0][af * 16 + lq * 4];
        f32x4 l1 = *(const f32x4*)&Ls2[1][af * 16 + lq * 4];
#pragma unroll
        for (int r = 0; r < 4; r++) rcp[af][r] = __builtin_amdgcn_rcpf(l0[r] + l1[r]);
    }

#pragma unroll
    for (int ct = 0; ct < 4; ct++) {
#pragma unroll
        for (int af = 0; af < 2; af++) {
            f32x4 o = acc[af][ct] * rcp[af];
            *(f32x4*)&scr[l15 * 40 + af * 16 + lq * 4] = o;
        }
        __asm__ volatile("s_waitcnt lgkmcnt(0)" ::: "memory");
#pragma unroll
        for (int pass = 0; pass < 2; pass++) {
            int c16 = pass * 8 + (l >> 3);
            int mi  = l & 7;
            f32x4 o4 = *(const f32x4*)&scr[c16 * 40 + mi * 4];
            int c = w * 64 + ct * 16 + c16;
            size_t gi = ((size_t)b * CC + c) * NN + m0 + mi * 4;
            f32x4 xr = *(const f32x4*)&x[gi];
            *(f32x4*)&out[gi] = o4 + xr;
        }
        __asm__ volatile("s_waitcnt lgkmcnt(0)" ::: "memory");
    }
}

extern "C" void kernel_launch(void* const* d_in, const int* in_sizes, int n_in,
                              void* d_out, int out_size, void* d_ws, size_t ws_size,
                              hipStream_t stream) {
    const float* x  = (const float*)d_in[0];
    const float* Wq = (const float*)d_in[1];
    const float* bq = (const float*)d_in[2];
    const float* Wk = (const float*)d_in[3];
    const float* bk = (const float*)d_in[4];
    const float* Wv = (const float*)d_in[5];
    const float* bv = (const float*)d_in[6];
    float* out = (float*)d_out;

    __bf16* qws = (__bf16*)d_ws;                       // B*N*32 bf16
    __bf16* kws = qws + (size_t)BB * NN * DKK;         // B*N*32 bf16
    __bf16* vws = kws + (size_t)BB * NN * DKK;         // B*C*N bf16
    __bf16* Wb  = vws + (size_t)BB * CC * NN;          // 320*256 bf16

    wconv_kernel<<<dim3(80), 256, 0, stream>>>(Wq, Wk, Wv, Wb);
    qkv_kernel<<<dim3(128, BB), 256, 0, stream>>>(x, bq, bk, bv, Wb, qws, kws, vws);
    attn_kernel<<<dim3(512), 256, 0, stream>>>(qws, kws, vws, x, out);
}

// Round 4
// 204.436 us; speedup vs baseline: 1.3551x; 1.3551x over previous
//
#include <hip/hip_runtime.h>
#include <hip/hip_bf16.h>
#include <math.h>

#define BB 4
#define CC 256
#define DKK 32
#define NN 4096
// 1/sqrt(32) * log2(e) — folded into q at QKV epilogue; attention uses exp2.
#define QSCALE 0.2550181864060454f

typedef __attribute__((ext_vector_type(8))) __bf16 bf16x8;
typedef __attribute__((ext_vector_type(4))) __bf16 bf16x4;
typedef __attribute__((ext_vector_type(4))) float f32x4;

// ---------------------------------------------------------------------------
// Kernel 0: W fp32 -> bf16, rows [Wq(32); Wk(32); Wv(256)] = Wb[320][256]
// ---------------------------------------------------------------------------
__global__ __launch_bounds__(256) void wconv_kernel(
    const float* __restrict__ Wq, const float* __restrict__ Wk,
    const float* __restrict__ Wv, __bf16* __restrict__ Wb)
{
    int i = (blockIdx.x * 256 + threadIdx.x) * 4;   // 80 blocks
    int row = i >> 8, col = i & 255;
    const float* src;
    if (row < 32)      src = &Wq[row * 256 + col];
    else if (row < 64) src = &Wk[(row - 32) * 256 + col];
    else               src = &Wv[(row - 64) * 256 + col];
    float4 v = *(const float4*)src;
    Wb[i]     = (__bf16)v.x;
    Wb[i + 1] = (__bf16)v.y;
    Wb[i + 2] = (__bf16)v.z;
    Wb[i + 3] = (__bf16)v.w;
}

// ---------------------------------------------------------------------------
// Kernel 0b: transpose x (B,C,N) fp32 -> xT (B,N,C) bf16 so qkv B-frags are
// direct 16B global loads (no LDS in qkv main loop).
// ---------------------------------------------------------------------------
__global__ __launch_bounds__(256) void xtrans_kernel(
    const float* __restrict__ x, __bf16* __restrict__ xT)
{
    __shared__ float xs[64][68];
    const int tid = threadIdx.x;
    const int n0 = blockIdx.x * 64;
    const int c0 = blockIdx.y * 64;
    const int b  = blockIdx.z;
#pragma unroll
    for (int p = 0; p < 4; p++) {
        int cc = p * 16 + (tid >> 4);
        int nf = (tid & 15) * 4;
        float4 v = *(const float4*)&x[((size_t)(b * CC + c0 + cc)) * NN + n0 + nf];
        xs[cc][nf] = v.x; xs[cc][nf + 1] = v.y; xs[cc][nf + 2] = v.z; xs[cc][nf + 3] = v.w;
    }
    __syncthreads();
    int n = tid >> 2, cs = (tid & 3) * 16;
    bf16x8 lo, hi;
#pragma unroll
    for (int j = 0; j < 8; j++) {
        lo[j] = (__bf16)xs[cs + j][n];
        hi[j] = (__bf16)xs[cs + 8 + j][n];
    }
    size_t base = ((size_t)(b * NN + n0 + n)) * CC + c0 + cs;
    *(bf16x8*)&xT[base]     = lo;
    *(bf16x8*)&xT[base + 8] = hi;
}

// ---------------------------------------------------------------------------
// Kernel 1: QKV projection — barrier-free MFMA GEMM (except epilogue).
// Block: 64 n-cols x 320 o-rows. Wave w -> o 80w..80w+79. Both operands
// straight from global (L2-hot). q/k transposed to (N,32) via LDS scratch.
// ---------------------------------------------------------------------------
__global__ __launch_bounds__(256) void qkv_kernel(
    const __bf16* __restrict__ xT, const __bf16* __restrict__ Wb,
    const float* __restrict__ bq, const float* __restrict__ bk,
    const float* __restrict__ bv,
    __bf16* __restrict__ qws, __bf16* __restrict__ kws, __bf16* __restrict__ vws)
{
    __shared__ float scr[64][68];

    const int tid = threadIdx.x;
    const int w   = tid >> 6;
    const int l   = tid & 63;
    const int l15 = l & 15;
    const int lq  = l >> 4;
    const int n0  = blockIdx.x * 64;
    const int b   = blockIdx.y;

    const f32x4 zf = {0.f, 0.f, 0.f, 0.f};
    f32x4 acc[5][4];
#pragma unroll
    for (int i = 0; i < 5; i++)
#pragma unroll
        for (int j = 0; j < 4; j++) acc[i][j] = zf;

#pragma unroll
    for (int ks = 0; ks < 8; ks++) {
        bf16x8 bfr[4];
#pragma unroll
        for (int nt = 0; nt < 4; nt++)
            bfr[nt] = *(const bf16x8*)&xT[((size_t)b * NN + n0 + nt * 16 + l15) * CC
                                          + ks * 32 + lq * 8];
#pragma unroll
        for (int ot = 0; ot < 5; ot++) {
            bf16x8 af = *(const bf16x8*)&Wb[(size_t)(80 * w + ot * 16 + l15) * CC
                                            + ks * 32 + lq * 8];
#pragma unroll
            for (int nt = 0; nt < 4; nt++)
                acc[ot][nt] = __builtin_amdgcn_mfma_f32_16x16x32_bf16(af, bfr[nt], acc[ot][nt], 0, 0, 0);
        }
    }

    // epilogue: D row o = 80w + ot*16 + lq*4 + r, col n = nt*16 + l15
#pragma unroll
    for (int ot = 0; ot < 5; ot++) {
        int ob = 80 * w + ot * 16;
#pragma unroll
        for (int nt = 0; nt < 4; nt++) {
#pragma unroll
            for (int r = 0; r < 4; r++) {
                int o = ob + lq * 4 + r;
                int n = nt * 16 + l15;
                float val = acc[ot][nt][r];
                if (ob >= 64) {
                    int c = o - 64;
                    vws[((size_t)b * CC + c) * NN + n0 + n] = (__bf16)(val + bv[c]);
                } else if (ob < 32) {
                    scr[o][n] = (val + bq[o]) * QSCALE;
                } else {
                    scr[o][n] = val + bk[o - 32];
                }
            }
        }
    }
    __syncthreads();
    {
        int n = tid >> 2, d0 = (tid & 3) * 8;
        bf16x8 qv, kv;
#pragma unroll
        for (int j = 0; j < 8; j++) {
            qv[j] = (__bf16)scr[d0 + j][n];
            kv[j] = (__bf16)scr[32 + d0 + j][n];
        }
        size_t base = ((size_t)b * NN + n0 + n) * DKK + d0;
        *(bf16x8*)&qws[base] = qv;
        *(bf16x8*)&kws[base] = kv;
    }
}

// ---------------------------------------------------------------------------
// Kernel 2: flash attention, restructured K-loop.
// Block: 64 m (grid 256, 1/CU), 4 waves. Wave w: PV for c-quarter 64w..64w+63
// over ALL 64 m (af=4 reg-reuse); QK^T computed TRANSPOSED (KQ^T) so D cols
// = m = lane&15 -> P is written in B-operand row-layout and l-norm is a
// per-lane scalar. V: global->reg->LDS double-buffer, multicast to 4 waves.
// Barriers are raw s_barrier + lgkmcnt(0) ONLY (no vmcnt drain): V/k
// prefetches for chunk i+1 stay in flight across the barrier; the compiler
// inserts exact vmcnt waits before the dependent ds_write/MFMA.
// ---------------------------------------------------------------------------
#define VST 40   // LDS row stride (bf16 elems): 80B rows -> <=2-way banks, 16B-aligned

__global__ __launch_bounds__(256, 1) void attn_kernel(
    const __bf16* __restrict__ qb, const __bf16* __restrict__ kb,
    const __bf16* __restrict__ vb, const float* __restrict__ x,
    float* __restrict__ out)
{
    __shared__ __align__(16) __bf16 vbuf[2][256 * VST];   // 40960 B
    __shared__ __align__(16) __bf16 pbuf[2][64 * VST];    // 10240 B
    __shared__ float Ls[4][32];

    const int tid = threadIdx.x;
    const int w   = tid >> 6;
    const int l   = tid & 63;
    const int l15 = l & 15;
    const int lq  = l >> 4;

    // XCD swizzle: batch pinned to an XCD pair -> K/V/Q stay L2-resident
    const int beta = blockIdx.x;
    const int b    = (beta >> 1) & 3;
    const int mt   = ((beta >> 3) << 1) | (beta & 1);   // 0..63
    const int m0   = mt * 64;

    const __bf16* qbb = qb + (size_t)b * NN * DKK;
    const __bf16* kbb = kb + (size_t)b * NN * DKK;
    const __bf16* vbb = vb + (size_t)b * CC * NN;

    // q B-frags for all 4 m-tiles (held whole kernel)
    bf16x8 qa[4];
#pragma unroll
    for (int af = 0; af < 4; af++)
        qa[af] = *(const bf16x8*)(qbb + (size_t)(m0 + af * 16 + l15) * DKK + lq * 8);

    const int vc   = tid >> 2;          // V stage: row base 0..63
    const int vs   = (tid & 3) * 8;     // seg offset (8 bf16 = 16 B)
    const int nsub = (w & 1) * 16;      // QK n-sub strip
    const int mh   = w >> 1;            // QK m-half

    const f32x4 zf = {0.f, 0.f, 0.f, 0.f};
    f32x4 acc[4][4];
#pragma unroll
    for (int i = 0; i < 4; i++)
#pragma unroll
        for (int j = 0; j < 4; j++) acc[i][j] = zf;
    float lacc0 = 0.f, lacc1 = 0.f;

    // prologue: stage chunk 0
    bf16x8 vreg[4];
#pragma unroll
    for (int p = 0; p < 4; p++)
        vreg[p] = *(const bf16x8*)(vbb + (size_t)(p * 64 + vc) * NN + vs);
    bf16x8 kfc = *(const bf16x8*)(kbb + (size_t)(nsub + l15) * DKK + lq * 8);
#pragma unroll
    for (int p = 0; p < 4; p++)
        *(bf16x8*)&vbuf[0][(p * 64 + vc) * VST + vs] = vreg[p];

    for (int ic = 0; ic < 128; ic++) {
        const int nc = ic * 32;
        const int cur = ic & 1;
        bf16x8 kfn;
        if (ic < 127) {
#pragma unroll
            for (int p = 0; p < 4; p++)
                vreg[p] = *(const bf16x8*)(vbb + (size_t)(p * 64 + vc) * NN + nc + 32 + vs);
            kfn = *(const bf16x8*)(kbb + (size_t)(nc + 32 + nsub + l15) * DKK + lq * 8);
        }

        // ---- KQ^T: D[n][m], this wave: 16n x 32m patch ----
        f32x4 e0 = __builtin_amdgcn_mfma_f32_16x16x32_bf16(kfc, qa[2 * mh],     zf, 0, 0, 0);
        f32x4 e1 = __builtin_amdgcn_mfma_f32_16x16x32_bf16(kfc, qa[2 * mh + 1], zf, 0, 0, 0);
        bf16x4 p0, p1;
#pragma unroll
        for (int r = 0; r < 4; r++) {
            float ev0 = __builtin_exp2f(e0[r]); lacc0 += ev0; p0[r] = (__bf16)ev0;
            float ev1 = __builtin_exp2f(e1[r]); lacc1 += ev1; p1[r] = (__bf16)ev1;
        }
        *(bf16x4*)&pbuf[cur][((2 * mh)     * 16 + l15) * VST + nsub + lq * 4] = p0;
        *(bf16x4*)&pbuf[cur][((2 * mh + 1) * 16 + l15) * VST + nsub + lq * 4] = p1;

        // publish P + V(ic) without draining vmem prefetches
        asm volatile("s_waitcnt lgkmcnt(0)\n\ts_barrier" ::: "memory");

        // ---- PV: O[c][m] += V[c][n] P[m][n], af reg-reuse x4 ----
        bf16x8 pf[4];
#pragma unroll
        for (int af = 0; af < 4; af++)
            pf[af] = *(const bf16x8*)&pbuf[cur][(af * 16 + l15) * VST + lq * 8];
#pragma unroll
        for (int ct = 0; ct < 4; ct++) {
            bf16x8 vf = *(const bf16x8*)&vbuf[cur][(w * 64 + ct * 16 + l15) * VST + lq * 8];
#pragma unroll
            for (int af = 0; af < 4; af++)
                acc[af][ct] = __builtin_amdgcn_mfma_f32_16x16x32_bf16(vf, pf[af], acc[af][ct], 0, 0, 0);
        }

        if (ic < 127) {
#pragma unroll
            for (int p = 0; p < 4; p++)
                *(bf16x8*)&vbuf[cur ^ 1][(p * 64 + vc) * VST + vs] = vreg[p];
            kfc = kfn;
        }
    }

    // ---- l: per-lane partials -> per-m sums ----
#pragma unroll
    for (int msk = 16; msk <= 32; msk <<= 1) {
        lacc0 += __shfl_xor(lacc0, msk, 64);
        lacc1 += __shfl_xor(lacc1, msk, 64);
    }
    if (l < 16) {
        Ls[w][l]      = lacc0;
        Ls[w][16 + l] = lacc1;
    }
    __syncthreads();

    // ---- epilogue: normalize (per-lane scalar), residual, store ----
#pragma unroll
    for (int af = 0; af < 4; af++) {
        int wpair = (af >> 1) * 2;
        float s = Ls[wpair][(af & 1) * 16 + l15] + Ls[wpair + 1][(af & 1) * 16 + l15];
        float rv = 1.0f / s;
#pragma unroll
        for (int ct = 0; ct < 4; ct++) {
#pragma unroll
            for (int r = 0; r < 4; r++) {
                int c = w * 64 + ct * 16 + lq * 4 + r;
                size_t gi = ((size_t)(b * CC + c)) * NN + m0 + af * 16 + l15;
                out[gi] = acc[af][ct][r] * rv + x[gi];
            }
        }
    }
}

extern "C" void kernel_launch(void* const* d_in, const int* in_sizes, int n_in,
                              void* d_out, int out_size, void* d_ws, size_t ws_size,
                              hipStream_t stream) {
    const float* x  = (const float*)d_in[0];
    const float* Wq = (const float*)d_in[1];
    const float* bq = (const float*)d_in[2];
    const float* Wk = (const float*)d_in[3];
    const float* bk = (const float*)d_in[4];
    const float* Wv = (const float*)d_in[5];
    const float* bv = (const float*)d_in[6];
    float* out = (float*)d_out;

    __bf16* qws = (__bf16*)d_ws;                       // B*N*32
    __bf16* kws = qws + (size_t)BB * NN * DKK;         // B*N*32
    __bf16* vws = kws + (size_t)BB * NN * DKK;         // B*C*N
    __bf16* Wb  = vws + (size_t)BB * CC * NN;          // 320*256
    __bf16* xT  = Wb  + (size_t)320 * CC;              // B*N*C

    wconv_kernel <<<dim3(80), 256, 0, stream>>>(Wq, Wk, Wv, Wb);
    xtrans_kernel<<<dim3(64, 4, BB), 256, 0, stream>>>(x, xT);
    qkv_kernel   <<<dim3(64, BB), 256, 0, stream>>>(xT, Wb, bq, bk, bv, qws, kws, vws);
    attn_kernel  <<<dim3(256), 256, 0, stream>>>(qws, kws, vws, x, out);
}